// Round 13
// baseline (11051.425 us; speedup 1.0000x reference)
//
#include <hip/hip_runtime.h>
#include <hip/hip_bf16.h>

typedef unsigned short ushort_t;
typedef unsigned int uint32;
typedef unsigned long long ull;
typedef short bf16x8 __attribute__((ext_vector_type(8)));
typedef float f32x4 __attribute__((ext_vector_type(4)));

#define Bb 64
#define Tt 512
#define Dd 512
#define Hh 1024
#define KK 1536
#define NBLK 32
#define OUT2_OFF 33554432ull
#define FLAGS_OFF 9699328ull
#define XB_OFF    9728000ull
#define XB_BYTES  33554432ull

// ws: HB @0 (128K) | RH @131072 (128K) | WT @262144 (9.4M) | flags @9699328 | XB @9728000 (32M opt)

__device__ inline ushort_t f2b(float f) {
    __hip_bfloat16 h = __float2bfloat16(f);
    return __builtin_bit_cast(ushort_t, h);
}
__device__ inline float b2f(ushort_t u) {
    uint32 x = ((uint32)u) << 16;
    return __builtin_bit_cast(float, x);
}
__device__ inline bf16x8 ld_bf8(const ushort_t* p) {
    uint4 v = *reinterpret_cast<const uint4*>(p);
    return __builtin_bit_cast(bf16x8, v);
}
__device__ inline bf16x8 ld_x8(const float* p) {
    float4 u = *reinterpret_cast<const float4*>(p);
    float4 v = *reinterpret_cast<const float4*>(p + 4);
    bf16x8 a;
    a[0] = (short)f2b(u.x); a[1] = (short)f2b(u.y); a[2] = (short)f2b(u.z); a[3] = (short)f2b(u.w);
    a[4] = (short)f2b(v.x); a[5] = (short)f2b(v.y); a[6] = (short)f2b(v.z); a[7] = (short)f2b(v.w);
    return a;
}
// LLC-coherent 16B load (bypass L1/L2); caller drains vmcnt before use.
__device__ inline uint4 ld_c16(const ushort_t* p) {
    uint4 d;
    asm volatile("global_load_dwordx4 %0, %1, off sc0 sc1" : "=v"(d) : "v"(p) : "memory");
    return d;
}
__device__ inline bf16x8 as_bf(uint4 v) { return __builtin_bit_cast(bf16x8, v); }
__device__ inline void st_a8(ushort_t* p, ull v) {
    __hip_atomic_store((ull*)p, v, __ATOMIC_RELAXED, __HIP_MEMORY_SCOPE_AGENT);
}
__device__ inline uint32 ld_flag(const uint32* p) {
    return __hip_atomic_load(p, __ATOMIC_RELAXED, __HIP_MEMORY_SCOPE_AGENT);
}
__device__ inline float sigm(float x) { return 1.f / (1.f + __expf(-x)); }

#define MFMA(a, b, c) __builtin_amdgcn_mfma_f32_16x16x32_bf16((a), (b), (c), 0, 0, 0)

__global__ __launch_bounds__(256) void k_init(const float* __restrict__ state,
                                              ushort_t* __restrict__ HB, uint32* flags) {
    int i = blockIdx.x * 256 + threadIdx.x;
    if (i < Bb * Hh) HB[i] = f2b(state[i]);
    if (i < 2112) flags[i] = 0;
}

__global__ __launch_bounds__(256) void k_xb(const float* __restrict__ inp,
                                            ushort_t* __restrict__ XB) {
    size_t i = ((size_t)blockIdx.x * 256 + threadIdx.x) * 8;
    bf16x8 v = ld_x8(inp + i);
    *reinterpret_cast<uint4*>(XB + i) = __builtin_bit_cast(uint4, v);
}

// WT[g][n][k] = bf16( k<512 ? Wx_g[k][n] : Wh_g[k-512][n] )
__global__ __launch_bounds__(256) void k_wt(const float* __restrict__ Wxz, const float* __restrict__ Whz,
                                            const float* __restrict__ Wxr, const float* __restrict__ Whr,
                                            const float* __restrict__ Wxh, const float* __restrict__ Whh,
                                            ushort_t* __restrict__ WT) {
    __shared__ float lds[64][65];
    int id = blockIdx.x;
    int g = id / 384, rem = id % 384, nt = rem / 24, kt = rem % 24;
    const float* Wx = (g == 0) ? Wxz : (g == 1) ? Wxr : Wxh;
    const float* Wh = (g == 0) ? Whz : (g == 1) ? Whr : Whh;
    int n0 = nt * 64, k0 = kt * 64;
    int tr = threadIdx.x >> 6, tc = threadIdx.x & 63;
    #pragma unroll
    for (int i = 0; i < 16; i++) {
        int kl = i * 4 + tr, k = k0 + kl;
        lds[kl][tc] = (k < 512) ? Wx[(size_t)k * Hh + n0 + tc]
                                : Wh[(size_t)(k - 512) * Hh + n0 + tc];
    }
    __syncthreads();
    #pragma unroll
    for (int i = 0; i < 16; i++) {
        int nl = i * 4 + tr;
        WT[((size_t)g * Hh + n0 + nl) * KK + k0 + tc] = f2b(lds[tc][nl]);
    }
}

// 32 blocks x 512 threads. Block owns cols [bi*32, +32). Wave w owns k-eighth
// [w*128,+128) of H/RH for ALL 4 m-tiles (block reads H exactly once), and
// finalizes output tile (fm = w>>1, fn = w&1) == acc tile index w = m*2+nt.
__global__ __launch_bounds__(512, 2) void gru_persist(
    const float* __restrict__ inp, const ushort_t* __restrict__ XB, int use_xb,
    const float* __restrict__ bz, const float* __restrict__ br, const float* __restrict__ bh,
    ushort_t* HB, ushort_t* RH, const ushort_t* __restrict__ WT,
    uint32* flags, float* __restrict__ out) {
    __shared__ ushort_t WX[2 * 2 * 16 * 512];   // z,r x-part, swizzled 1KB tiles: 65536 B
    __shared__ float    RED[8 * 8 * 64 * 4];    // [tile][srcwave][lane][4]: 65536 B
    __shared__ ushort_t STG[8 * 256];           // 4096 B   (total 135168 <= 160KiB)

    const int bi = blockIdx.x;
    const int tid = threadIdx.x;
    const int l = tid & 63, w = tid >> 6;
    const int lrow = l & 15, lq = l >> 4;
    const int wloff = lrow * 32 + (lq ^ ((lrow >> 1) & 3)) * 8;

    // ---- stage z,r x-part weight tiles into swizzled LDS ----
    for (int idx = tid; idx < 4096; idx += 512) {    // 64 tiles x 64 16B-chunks
        int tile = idx >> 6, chunk = idx & 63;
        int g = tile >> 5, nt = (tile >> 4) & 1, ks = tile & 15;
        int col = chunk >> 2, slot = chunk & 3;
        const ushort_t* src = WT + ((size_t)g * Hh + bi * 32 + nt * 16 + col) * KK + ks * 32 + slot * 8;
        *reinterpret_cast<uint4*>(WX + ((g * 2 + nt) * 16 + ks) * 512 + col * 32 +
                                  (slot ^ ((col >> 1) & 3)) * 8) =
            *reinterpret_cast<const uint4*>(src);
    }
    #define WXT(g, nt, ks) ld_bf8(WX + (((g) * 2 + (nt)) * 16 + (ks)) * 512 + wloff)

    // ---- per-wave register weights: z/r/h H-part k-eighth + h x-part k-eighth ----
    bf16x8 Wzh[2][4], Wrh[2][4], Whh_[2][4], Whx[2][2];
    #pragma unroll
    for (int nt = 0; nt < 2; nt++) {
        #pragma unroll
        for (int j = 0; j < 4; j++) {
            const ushort_t* base = WT + ((size_t)0 * Hh + bi * 32 + nt * 16 + lrow) * KK
                                      + 512 + w * 128 + j * 32 + lq * 8;
            Wzh[nt][j]  = ld_bf8(base);
            Wrh[nt][j]  = ld_bf8(base + (size_t)Hh * KK);
            Whh_[nt][j] = ld_bf8(base + (size_t)2 * Hh * KK);
        }
        #pragma unroll
        for (int j = 0; j < 2; j++)
            Whx[nt][j] = ld_bf8(WT + ((size_t)2 * Hh + bi * 32 + nt * 16 + lrow) * KK
                                   + w * 64 + j * 32 + lq * 8);
    }

    // A-operand bases: row = m*16+lrow; H k-eighth w*128; x k-eighth w*64
    const ushort_t* hbB = HB + (size_t)lrow * Hh + w * 128 + lq * 8;
    const ushort_t* rbB = RH + (size_t)lrow * Hh + w * 128 + lq * 8;
    const float*    xFb = inp + (size_t)lrow * (Tt * Dd) + w * 64 + lq * 8;
    const ushort_t* xBb = XB + (size_t)lrow * (Tt * Dd) + w * 64 + lq * 8;

    // finalizer tile (fm, fn) — MUST match acc tile id w = m*2 + nt
    const int fm = w >> 1, fn = w & 1;
    const int ncol = bi * 32 + fn * 16 + lrow;
    const float bzv = bz[ncol], brv = br[ncol], bhv = bh[ncol];
    const size_t strow = (size_t)(fm * 16 + (l >> 2)) * Hh + bi * 32 + fn * 16 + (l & 3) * 4;
    ushort_t* stW = &STG[w * 256];
    const int stg_rd = w * 256 + (l >> 2) * 16 + (l & 3) * 4;

    float hold[4];
    #pragma unroll
    for (int j = 0; j < 4; j++)
        hold[j] = b2f(HB[(size_t)(fm * 16 + lq * 4 + j) * Hh + ncol]);

    __syncthreads();

    const f32x4 z4 = {0.f, 0.f, 0.f, 0.f};
    #define RED_AT(tile, src) reinterpret_cast<f32x4*>(&RED[(((tile) * 8 + (src)) * 64 + l) * 4])

    for (int t = 0; t < Tt; ++t) {
        const uint32 valH = 2u * (uint32)t;
        const uint32 valR = 2u * (uint32)t + 1u;

        // ---- wait H(t): fast all-32 check, else only this wave's 4 producers ----
        {
            uint32 v = ld_flag(flags + (l & 31) * 32);
            if (!__all((int)(v >= valH))) {
                uint32 vv = ld_flag(flags + (w * 4 + (l & 3)) * 32);
                while (__any((int)(vv < valH))) {
                    __builtin_amdgcn_s_sleep(1);
                    vv = ld_flag(flags + (w * 4 + (l & 3)) * 32);
                }
            }
        }
        // burst: H k-eighth for 4 m-tiles (16 x 1KB scoped loads)
        uint4 Hf[16];
        #pragma unroll
        for (int m = 0; m < 4; m++)
            #pragma unroll
            for (int j = 0; j < 4; j++)
                Hf[m * 4 + j] = ld_c16(hbB + (size_t)m * 16 * Hh + j * 32);
        asm volatile("s_waitcnt vmcnt(0)" ::: "memory");
        __builtin_amdgcn_sched_barrier(0);

        // x fragments (k-eighth, 4 m-tiles)
        bf16x8 xf[8];
        if (use_xb) {
            #pragma unroll
            for (int m = 0; m < 4; m++)
                #pragma unroll
                for (int j = 0; j < 2; j++)
                    xf[m * 2 + j] = ld_bf8(xBb + (size_t)m * 16 * (Tt * Dd) + (size_t)t * Dd + j * 32);
        } else {
            #pragma unroll
            for (int m = 0; m < 4; m++)
                #pragma unroll
                for (int j = 0; j < 2; j++)
                    xf[m * 2 + j] = ld_x8(xFb + (size_t)m * 16 * (Tt * Dd) + (size_t)t * Dd + j * 32);
        }

        // ---- z round: partials, reduce ----
        {
            f32x4 acc[8];
            #pragma unroll
            for (int m = 0; m < 4; m++)
                #pragma unroll
                for (int nt = 0; nt < 2; nt++) {
                    f32x4 a = z4;
                    #pragma unroll
                    for (int j = 0; j < 4; j++) a = MFMA(as_bf(Hf[m * 4 + j]), Wzh[nt][j], a);
                    #pragma unroll
                    for (int j = 0; j < 2; j++) a = MFMA(xf[m * 2 + j], WXT(0, nt, w * 2 + j), a);
                    acc[m * 2 + nt] = a;
                }
            #pragma unroll
            for (int i = 0; i < 8; i++) *RED_AT(i, w) = acc[i];
        }
        __syncthreads();
        f32x4 azf = z4;
        #pragma unroll
        for (int s = 0; s < 8; s++) azf += *RED_AT(w, s);
        __syncthreads();

        // ---- r round ----
        {
            f32x4 acc[8];
            #pragma unroll
            for (int m = 0; m < 4; m++)
                #pragma unroll
                for (int nt = 0; nt < 2; nt++) {
                    f32x4 a = z4;
                    #pragma unroll
                    for (int j = 0; j < 4; j++) a = MFMA(as_bf(Hf[m * 4 + j]), Wrh[nt][j], a);
                    #pragma unroll
                    for (int j = 0; j < 2; j++) a = MFMA(xf[m * 2 + j], WXT(1, nt, w * 2 + j), a);
                    acc[m * 2 + nt] = a;
                }
            #pragma unroll
            for (int i = 0; i < 8; i++) *RED_AT(i, w) = acc[i];
        }
        __syncthreads();
        f32x4 arf = z4;
        #pragma unroll
        for (int s = 0; s < 8; s++) arf += *RED_AT(w, s);
        __syncthreads();

        // ---- finalize z, r; store RH tile ----
        float zreg[4];
        #pragma unroll
        for (int j = 0; j < 4; j++) {
            zreg[j] = sigm(azf[j] + bzv);
            float rr = sigm(arf[j] + brv);
            stW[(lq * 4 + j) * 16 + lrow] = f2b(rr * hold[j]);
        }
        asm volatile("s_waitcnt lgkmcnt(0)" ::: "memory");
        st_a8(RH + strow, *reinterpret_cast<const ull*>(&STG[stg_rd]));
        asm volatile("s_waitcnt vmcnt(0)" ::: "memory");
        __syncthreads();
        if (tid == 0)
            __hip_atomic_store(flags + (uint32)bi * 32, valR,
                               __ATOMIC_RELAXED, __HIP_MEMORY_SCOPE_AGENT);

        // ---- wait RH(t) ----
        {
            uint32 v = ld_flag(flags + (l & 31) * 32);
            if (!__all((int)(v >= valR))) {
                uint32 vv = ld_flag(flags + (w * 4 + (l & 3)) * 32);
                while (__any((int)(vv < valR))) {
                    __builtin_amdgcn_s_sleep(1);
                    vv = ld_flag(flags + (w * 4 + (l & 3)) * 32);
                }
            }
        }
        uint4 Rf[16];
        #pragma unroll
        for (int m = 0; m < 4; m++)
            #pragma unroll
            for (int j = 0; j < 4; j++)
                Rf[m * 4 + j] = ld_c16(rbB + (size_t)m * 16 * Hh + j * 32);
        asm volatile("s_waitcnt vmcnt(0)" ::: "memory");
        __builtin_amdgcn_sched_barrier(0);

        // ---- h round: (R*H)@W_hh k-eighth + x-part ----
        {
            f32x4 acc[8];
            #pragma unroll
            for (int m = 0; m < 4; m++)
                #pragma unroll
                for (int nt = 0; nt < 2; nt++) {
                    f32x4 a = z4;
                    #pragma unroll
                    for (int j = 0; j < 4; j++) a = MFMA(as_bf(Rf[m * 4 + j]), Whh_[nt][j], a);
                    #pragma unroll
                    for (int j = 0; j < 2; j++) a = MFMA(xf[m * 2 + j], Whx[nt][j], a);
                    acc[m * 2 + nt] = a;
                }
            #pragma unroll
            for (int i = 0; i < 8; i++) *RED_AT(i, w) = acc[i];
        }
        __syncthreads();
        f32x4 ahf = z4;
        #pragma unroll
        for (int s = 0; s < 8; s++) ahf += *RED_AT(w, s);
        __syncthreads();

        // ---- finalize H(t+1) ----
        float hn[4];
        #pragma unroll
        for (int j = 0; j < 4; j++) {
            float pre = ahf[j] + bhv;
            float e = __expf(-2.f * fabsf(pre));
            float th = (1.f - e) / (1.f + e);
            th = copysignf(th, pre);
            float v = zreg[j] * hold[j] + (1.f - zreg[j]) * th;
            hold[j] = v;
            hn[j] = v;
            stW[(lq * 4 + j) * 16 + lrow] = f2b(v);
        }
        asm volatile("s_waitcnt lgkmcnt(0)" ::: "memory");
        st_a8(HB + strow, *reinterpret_cast<const ull*>(&STG[stg_rd]));
        asm volatile("s_waitcnt vmcnt(0)" ::: "memory");
        __syncthreads();
        if (tid == 0)
            __hip_atomic_store(flags + (uint32)bi * 32, valR + 1u,
                               __ATOMIC_RELAXED, __HIP_MEMORY_SCOPE_AGENT);

        // out stores after the flag (plain cached; flushed at kernel end)
        *reinterpret_cast<float4*>(out + (size_t)ncol * (Tt * Bb) + (size_t)t * Bb + fm * 16 + lq * 4) =
            make_float4(hn[0], hn[1], hn[2], hn[3]);
        if (t == Tt - 1) {
            #pragma unroll
            for (int j = 0; j < 4; j++)
                out[OUT2_OFF + (size_t)(fm * 16 + lq * 4 + j) * Hh + ncol] = hn[j];
        }
    }
    #undef WXT
    #undef RED_AT
}

extern "C" void kernel_launch(void* const* d_in, const int* in_sizes, int n_in,
                              void* d_out, int out_size, void* d_ws, size_t ws_size,
                              hipStream_t stream) {
    const float* inp   = (const float*)d_in[0];
    const float* state = (const float*)d_in[1];
    const float* Wxz   = (const float*)d_in[2];
    const float* Whz   = (const float*)d_in[3];
    const float* bz    = (const float*)d_in[4];
    const float* Wxr   = (const float*)d_in[5];
    const float* Whr   = (const float*)d_in[6];
    const float* br    = (const float*)d_in[7];
    const float* Wxh   = (const float*)d_in[8];
    const float* Whh   = (const float*)d_in[9];
    const float* bh    = (const float*)d_in[10];
    float* out = (float*)d_out;

    char* ws = (char*)d_ws;
    ushort_t* HB    = (ushort_t*)(ws);
    ushort_t* RH    = (ushort_t*)(ws + 131072);
    ushort_t* WT    = (ushort_t*)(ws + 262144);
    uint32*   flags = (uint32*)(ws + FLAGS_OFF);
    ushort_t* XB    = (ushort_t*)(ws + XB_OFF);
    int use_xb = (ws_size >= XB_OFF + XB_BYTES) ? 1 : 0;

    k_init<<<dim3(256), dim3(256), 0, stream>>>(state, HB, flags);
    k_wt<<<dim3(1152), dim3(256), 0, stream>>>(Wxz, Whz, Wxr, Whr, Wxh, Whh, WT);
    if (use_xb)
        k_xb<<<dim3(8192), dim3(256), 0, stream>>>(inp, XB);

    void* args[] = {(void*)&inp, (void*)&XB, (void*)&use_xb,
                    (void*)&bz, (void*)&br, (void*)&bh,
                    (void*)&HB, (void*)&RH, (void*)&WT, (void*)&flags, (void*)&out};
    hipError_t e = hipLaunchCooperativeKernel((const void*)gru_persist, dim3(NBLK), dim3(512),
                                              args, 0, stream);
    if (e != hipSuccess) {
        gru_persist<<<dim3(NBLK), dim3(512), 0, stream>>>(inp, XB, use_xb, bz, br, bh,
                                                          HB, RH, WT, flags, out);
    }
}

// Round 14
// 9130.386 us; speedup vs baseline: 1.2104x; 1.2104x over previous
//
#include <hip/hip_runtime.h>
#include <hip/hip_bf16.h>

typedef unsigned short ushort_t;
typedef unsigned int uint32;
typedef unsigned long long ull;
typedef short bf16x8 __attribute__((ext_vector_type(8)));
typedef float f32x4 __attribute__((ext_vector_type(4)));

#define Bb 64
#define Tt 512
#define Dd 512
#define Hh 1024
#define KK 1536
#define NBLK 64
#define OUT2_OFF 33554432ull

// common: WT @262144 (9.4M) | flags @9699328 (28K pad)
// fallback: HB @0 | RH @131072 | XB @9728000 (32M)   [R8 layout]
// ring:     HBR @16777216 (516 slots x 128K) | RHR @84410368 (516 slots) | XB @152043520
#define WT_OFF      262144ull
#define FLAGS_OFF   9699328ull
#define XB_SMALL    9728000ull
#define HBR_OFF     16777216ull
#define RING_BYTES  67633152ull       // 516 * 131072
#define RHR_OFF     (HBR_OFF + RING_BYTES)
#define XB_BIG      (RHR_OFF + RING_BYTES)
#define NEED_RING   XB_BIG
#define NEED_XB_BIG (XB_BIG + 33554432ull)
#define NEED_XB_SM  (XB_SMALL + 33554432ull)

__device__ inline ushort_t f2b(float f) {
    __hip_bfloat16 h = __float2bfloat16(f);
    return __builtin_bit_cast(ushort_t, h);
}
__device__ inline float b2f(ushort_t u) {
    uint32 x = ((uint32)u) << 16;
    return __builtin_bit_cast(float, x);
}
__device__ inline bf16x8 ld_bf8(const ushort_t* p) {
    uint4 v = *reinterpret_cast<const uint4*>(p);
    return __builtin_bit_cast(bf16x8, v);
}
__device__ inline bf16x8 ld_x8(const float* p) {
    float4 u = *reinterpret_cast<const float4*>(p);
    float4 v = *reinterpret_cast<const float4*>(p + 4);
    bf16x8 a;
    a[0] = (short)f2b(u.x); a[1] = (short)f2b(u.y); a[2] = (short)f2b(u.z); a[3] = (short)f2b(u.w);
    a[4] = (short)f2b(v.x); a[5] = (short)f2b(v.y); a[6] = (short)f2b(v.z); a[7] = (short)f2b(v.w);
    return a;
}
// LLC-coherent 16B load (bypass L1/L2); caller drains vmcnt before use. (fallback path)
__device__ inline uint4 ld_c16(const ushort_t* p) {
    uint4 d;
    asm volatile("global_load_dwordx4 %0, %1, off sc0 sc1" : "=v"(d) : "v"(p) : "memory");
    return d;
}
__device__ inline bf16x8 as_bf(uint4 v) { return __builtin_bit_cast(bf16x8, v); }
__device__ inline void st_a8(ushort_t* p, ull v) {
    __hip_atomic_store((ull*)p, v, __ATOMIC_RELAXED, __HIP_MEMORY_SCOPE_AGENT);
}
__device__ inline uint32 ld_flag(const uint32* p) {
    return __hip_atomic_load(p, __ATOMIC_RELAXED, __HIP_MEMORY_SCOPE_AGENT);
}
__device__ inline float sigm(float x) { return 1.f / (1.f + __expf(-x)); }

#define MFMA(a, b, c) __builtin_amdgcn_mfma_f32_16x16x32_bf16((a), (b), (c), 0, 0, 0)

__global__ __launch_bounds__(256) void k_init(const float* __restrict__ state,
                                              ushort_t* __restrict__ HB0, uint32* flags) {
    int i = blockIdx.x * 256 + threadIdx.x;
    if (i < Bb * Hh) HB0[i] = f2b(state[i]);
    if (i < 2112) flags[i] = 0;
}

__global__ __launch_bounds__(256) void k_xb(const float* __restrict__ inp,
                                            ushort_t* __restrict__ XB) {
    size_t i = ((size_t)blockIdx.x * 256 + threadIdx.x) * 8;
    bf16x8 v = ld_x8(inp + i);
    *reinterpret_cast<uint4*>(XB + i) = __builtin_bit_cast(uint4, v);
}

// WT[g][n][k] = bf16( k<512 ? Wx_g[k][n] : Wh_g[k-512][n] )
__global__ __launch_bounds__(256) void k_wt(const float* __restrict__ Wxz, const float* __restrict__ Whz,
                                            const float* __restrict__ Wxr, const float* __restrict__ Whr,
                                            const float* __restrict__ Wxh, const float* __restrict__ Whh,
                                            ushort_t* __restrict__ WT) {
    __shared__ float lds[64][65];
    int id = blockIdx.x;
    int g = id / 384, rem = id % 384, nt = rem / 24, kt = rem % 24;
    const float* Wx = (g == 0) ? Wxz : (g == 1) ? Wxr : Wxh;
    const float* Wh = (g == 0) ? Whz : (g == 1) ? Whr : Whh;
    int n0 = nt * 64, k0 = kt * 64;
    int tr = threadIdx.x >> 6, tc = threadIdx.x & 63;
    #pragma unroll
    for (int i = 0; i < 16; i++) {
        int kl = i * 4 + tr, k = k0 + kl;
        lds[kl][tc] = (k < 512) ? Wx[(size_t)k * Hh + n0 + tc]
                                : Wh[(size_t)(k - 512) * Hh + n0 + tc];
    }
    __syncthreads();
    #pragma unroll
    for (int i = 0; i < 16; i++) {
        int nl = i * 4 + tr;
        WT[((size_t)g * Hh + n0 + nl) * KK + k0 + tc] = f2b(lds[tc][nl]);
    }
}

// RING=1: HB/RH rotate through 512 x 128KB virgin slots -> consumers use PLAIN CACHED
// loads (no stale line can exist: addresses written exactly once, flag-ordered).
// RING=0: R8 fallback — scoped (sc0 sc1) consumer loads, single-buffer HB/RH.
template <int RING>
__global__ __launch_bounds__(256, 1) void gru_persist(
    const float* __restrict__ inp, const ushort_t* __restrict__ XB, int use_xb,
    const float* __restrict__ bz, const float* __restrict__ br, const float* __restrict__ bh,
    ushort_t* HBR, ushort_t* RHR, const ushort_t* __restrict__ WT,
    uint32* flags, float* __restrict__ out) {
    __shared__ ushort_t WL[3 * 48 * 512];   // 147456 B, slot-XOR-swizzled 1KB tiles
    __shared__ ushort_t STG[4 * 256];       // per-wave 16x16 store-coalescing tile

    const int bi = blockIdx.x;
    const int tid = threadIdx.x;

    for (int idx = tid; idx < 9216; idx += 256) {
        int g = idx / 3072, r = idx % 3072, col = r / 192, c8 = r % 192;
        int kc = c8 >> 2, slot = c8 & 3, ps = slot ^ ((col >> 1) & 3);
        const ushort_t* src = WT + ((size_t)g * Hh + bi * 16 + col) * KK + c8 * 8;
        *reinterpret_cast<uint4*>(WL + g * 24576 + kc * 512 + col * 32 + ps * 8) =
            *reinterpret_cast<const uint4*>(src);
    }

    const int l = tid & 63, w = tid >> 6;
    const int lrow = l & 15, lq = l >> 4;
    const int ncol = bi * 16 + lrow;
    const int wloff = lrow * 32 + (lq ^ ((lrow >> 1) & 3)) * 8;
    const int c0 = (bi + w) & 3;

    #define WTILE(g, kc) ld_bf8(WL + (g) * 24576 + (kc) * 512 + wloff)

    const int arow = w * 16 + lrow;
    const float*    xF = inp + (size_t)arow * (Tt * Dd) + lq * 8;
    const ushort_t* xBp = XB + (size_t)arow * (Tt * Dd) + lq * 8;
    const ushort_t* hb = HBR + arow * Hh + lq * 8;     // + slot offset per t
    const ushort_t* rb = RHR + arow * Hh + lq * 8;
    const float bzv = bz[ncol], brv = br[ncol], bhv = bh[ncol];

    const size_t strow  = (size_t)(w * 16 + (l >> 2)) * Hh + bi * 16 + (l & 3) * 4;
    const int    stg_wr = w * 256;
    const int    stg_rd = w * 256 + (l >> 2) * 16 + (l & 3) * 4;

    float hold[4];
    #pragma unroll
    for (int j = 0; j < 4; j++)
        hold[j] = b2f(HBR[(size_t)(w * 16 + lq * 4 + j) * Hh + ncol]);  // slot 0

    __syncthreads();

    const f32x4 z4 = {0.f, 0.f, 0.f, 0.f};
    f32x4 az = z4, ar = z4, ahx = z4;

    bf16x8 xa[16];
    if (use_xb) {
        #pragma unroll
        for (int i = 0; i < 16; i++) xa[i] = ld_bf8(xBp + i * 32);
    } else {
        #pragma unroll
        for (int i = 0; i < 16; i++) xa[i] = ld_x8(xF + i * 32);
    }
    #pragma unroll
    for (int kk = 0; kk < 16; kk++) {
        az  = MFMA(xa[kk], WTILE(0, kk), az);
        ar  = MFMA(xa[kk], WTILE(1, kk), ar);
        ahx = MFMA(xa[kk], WTILE(2, kk), ahx);
    }

    for (int t = 0; t < Tt; ++t) {
        const uint32 valH = 2u * (uint32)t;
        const uint32 valR = 2u * (uint32)t + 1u;
        const size_t tb  = RING ? ((size_t)t << 16) : 0;        // 65536 elem/slot
        const size_t tb1 = RING ? ((size_t)(t + 1) << 16) : 0;

        // ================= PHASE A: consume H(t) =================
        {
            uint32 v = ld_flag(flags + l * 32);
            if (__all((int)(v >= valH))) {
                asm volatile("" ::: "memory");
                if (RING) {
                    #pragma unroll
                    for (int kk = 0; kk < 32; kk++) {
                        bf16x8 A = ld_bf8(hb + tb + kk * 32);
                        az = MFMA(A, WTILE(0, 16 + kk), az);
                        ar = MFMA(A, WTILE(1, 16 + kk), ar);
                    }
                } else {
                    uint4 A[32];
                    #pragma unroll
                    for (int i = 0; i < 32; i++) A[i] = ld_c16(hb + i * 32);
                    asm volatile("s_waitcnt vmcnt(0)" ::: "memory");
                    __builtin_amdgcn_sched_barrier(0);
                    #pragma unroll
                    for (int kk = 0; kk < 32; kk++) {
                        az = MFMA(as_bf(A[kk]), WTILE(0, 16 + kk), az);
                        ar = MFMA(as_bf(A[kk]), WTILE(1, 16 + kk), ar);
                    }
                }
            } else {
                for (int ci = 0; ci < 4; ci++) {
                    int c = (c0 + ci) & 3;
                    uint32 vv = ld_flag(flags + (c * 16 + (l & 15)) * 32);
                    while (__any((int)(vv < valH))) {
                        __builtin_amdgcn_s_sleep(1);
                        vv = ld_flag(flags + (c * 16 + (l & 15)) * 32);
                    }
                    asm volatile("" ::: "memory");
                    if (RING) {
                        #pragma unroll
                        for (int i = 0; i < 8; i++) {
                            int kk = c * 8 + i;
                            bf16x8 A = ld_bf8(hb + tb + kk * 32);
                            az = MFMA(A, WTILE(0, 16 + kk), az);
                            ar = MFMA(A, WTILE(1, 16 + kk), ar);
                        }
                    } else {
                        uint4 A[8];
                        #pragma unroll
                        for (int i = 0; i < 8; i++) A[i] = ld_c16(hb + (c * 8 + i) * 32);
                        asm volatile("s_waitcnt vmcnt(0)" ::: "memory");
                        __builtin_amdgcn_sched_barrier(0);
                        #pragma unroll
                        for (int i = 0; i < 8; i++) {
                            int kk = c * 8 + i;
                            az = MFMA(as_bf(A[i]), WTILE(0, 16 + kk), az);
                            ar = MFMA(as_bf(A[i]), WTILE(1, 16 + kk), ar);
                        }
                    }
                }
            }
        }
        float zreg[4];
        #pragma unroll
        for (int j = 0; j < 4; j++) {
            zreg[j] = sigm(az[j] + bzv);
            float rr = sigm(ar[j] + brv);
            STG[stg_wr + (lq * 4 + j) * 16 + lrow] = f2b(rr * hold[j]);
        }
        asm volatile("s_waitcnt lgkmcnt(0)" ::: "memory");
        st_a8(RHR + strow + tb, *reinterpret_cast<const ull*>(&STG[stg_rd]));
        asm volatile("s_waitcnt vmcnt(0)" ::: "memory");
        __syncthreads();
        if (tid == 0)
            __hip_atomic_store(flags + (uint32)bi * 32, valR,
                               __ATOMIC_RELAXED, __HIP_MEMORY_SCOPE_AGENT);

        if (t < Tt - 1) {
            if (use_xb) {
                #pragma unroll
                for (int i = 0; i < 16; i++) xa[i] = ld_bf8(xBp + (size_t)(t + 1) * Dd + i * 32);
            } else {
                #pragma unroll
                for (int i = 0; i < 16; i++) xa[i] = ld_x8(xF + (size_t)(t + 1) * Dd + i * 32);
            }
        }

        // ================= PHASE B: consume RH(t) =================
        f32x4 ah0 = ahx, ah1 = z4;
        {
            uint32 v = ld_flag(flags + l * 32);
            if (__all((int)(v >= valR))) {
                asm volatile("" ::: "memory");
                if (RING) {
                    #pragma unroll
                    for (int kk = 0; kk < 32; kk += 2) {
                        bf16x8 A0 = ld_bf8(rb + tb + kk * 32);
                        bf16x8 A1 = ld_bf8(rb + tb + kk * 32 + 32);
                        ah0 = MFMA(A0, WTILE(2, 16 + kk),     ah0);
                        ah1 = MFMA(A1, WTILE(2, 16 + kk + 1), ah1);
                    }
                } else {
                    uint4 A[32];
                    #pragma unroll
                    for (int i = 0; i < 32; i++) A[i] = ld_c16(rb + i * 32);
                    asm volatile("s_waitcnt vmcnt(0)" ::: "memory");
                    __builtin_amdgcn_sched_barrier(0);
                    #pragma unroll
                    for (int kk = 0; kk < 32; kk += 2) {
                        ah0 = MFMA(as_bf(A[kk]),     WTILE(2, 16 + kk),     ah0);
                        ah1 = MFMA(as_bf(A[kk + 1]), WTILE(2, 16 + kk + 1), ah1);
                    }
                }
            } else {
                for (int ci = 0; ci < 4; ci++) {
                    int c = (c0 + ci) & 3;
                    uint32 vv = ld_flag(flags + (c * 16 + (l & 15)) * 32);
                    while (__any((int)(vv < valR))) {
                        __builtin_amdgcn_s_sleep(1);
                        vv = ld_flag(flags + (c * 16 + (l & 15)) * 32);
                    }
                    asm volatile("" ::: "memory");
                    if (RING) {
                        #pragma unroll
                        for (int i = 0; i < 8; i++) {
                            int kk = c * 8 + i;
                            bf16x8 A = ld_bf8(rb + tb + kk * 32);
                            if (i & 1) ah1 = MFMA(A, WTILE(2, 16 + kk), ah1);
                            else       ah0 = MFMA(A, WTILE(2, 16 + kk), ah0);
                        }
                    } else {
                        uint4 A[8];
                        #pragma unroll
                        for (int i = 0; i < 8; i++) A[i] = ld_c16(rb + (c * 8 + i) * 32);
                        asm volatile("s_waitcnt vmcnt(0)" ::: "memory");
                        __builtin_amdgcn_sched_barrier(0);
                        #pragma unroll
                        for (int i = 0; i < 8; i++) {
                            int kk = c * 8 + i;
                            if (i & 1) ah1 = MFMA(as_bf(A[i]), WTILE(2, 16 + kk), ah1);
                            else       ah0 = MFMA(as_bf(A[i]), WTILE(2, 16 + kk), ah0);
                        }
                    }
                }
            }
        }
        f32x4 aht = ah0 + ah1;
        float hn[4];
        #pragma unroll
        for (int j = 0; j < 4; j++) {
            float pre = aht[j] + bhv;
            float e = __expf(-2.f * fabsf(pre));
            float th = (1.f - e) / (1.f + e);
            th = copysignf(th, pre);
            float v = zreg[j] * hold[j] + (1.f - zreg[j]) * th;
            hold[j] = v;
            hn[j] = v;
            STG[stg_wr + (lq * 4 + j) * 16 + lrow] = f2b(v);
        }
        asm volatile("s_waitcnt lgkmcnt(0)" ::: "memory");
        st_a8(HBR + strow + tb1, *reinterpret_cast<const ull*>(&STG[stg_rd]));
        asm volatile("s_waitcnt vmcnt(0)" ::: "memory");
        __syncthreads();
        if (tid == 0)
            __hip_atomic_store(flags + (uint32)bi * 32, valR + 1u,
                               __ATOMIC_RELAXED, __HIP_MEMORY_SCOPE_AGENT);

        *reinterpret_cast<float4*>(out + (size_t)ncol * (Tt * Bb) + (size_t)t * Bb + w * 16 + lq * 4) =
            make_float4(hn[0], hn[1], hn[2], hn[3]);
        if (t == Tt - 1) {
            #pragma unroll
            for (int j = 0; j < 4; j++)
                out[OUT2_OFF + (size_t)(w * 16 + lq * 4 + j) * Hh + ncol] = hn[j];
        }

        az = z4; ar = z4; ahx = z4;
        if (t < Tt - 1) {
            #pragma unroll
            for (int kk = 0; kk < 16; kk++) {
                az  = MFMA(xa[kk], WTILE(0, kk), az);
                ar  = MFMA(xa[kk], WTILE(1, kk), ar);
                ahx = MFMA(xa[kk], WTILE(2, kk), ahx);
            }
        }
    }
    #undef WTILE
}

extern "C" void kernel_launch(void* const* d_in, const int* in_sizes, int n_in,
                              void* d_out, int out_size, void* d_ws, size_t ws_size,
                              hipStream_t stream) {
    const float* inp   = (const float*)d_in[0];
    const float* state = (const float*)d_in[1];
    const float* Wxz   = (const float*)d_in[2];
    const float* Whz   = (const float*)d_in[3];
    const float* bz    = (const float*)d_in[4];
    const float* Wxr   = (const float*)d_in[5];
    const float* Whr   = (const float*)d_in[6];
    const float* br    = (const float*)d_in[7];
    const float* Wxh   = (const float*)d_in[8];
    const float* Whh   = (const float*)d_in[9];
    const float* bh    = (const float*)d_in[10];
    float* out = (float*)d_out;

    char* ws = (char*)d_ws;
    ushort_t* WT    = (ushort_t*)(ws + WT_OFF);
    uint32*   flags = (uint32*)(ws + FLAGS_OFF);

    const int ring = (ws_size >= NEED_RING) ? 1 : 0;
    ushort_t* HB = ring ? (ushort_t*)(ws + HBR_OFF) : (ushort_t*)ws;
    ushort_t* RH = ring ? (ushort_t*)(ws + RHR_OFF) : (ushort_t*)(ws + 131072);
    ushort_t* XB = ring ? (ushort_t*)(ws + XB_BIG)  : (ushort_t*)(ws + XB_SMALL);
    int use_xb = ring ? (ws_size >= NEED_XB_BIG ? 1 : 0)
                      : (ws_size >= NEED_XB_SM  ? 1 : 0);

    k_init<<<dim3(256), dim3(256), 0, stream>>>(state, HB, flags);
    k_wt<<<dim3(1152), dim3(256), 0, stream>>>(Wxz, Whz, Wxr, Whr, Wxh, Whh, WT);
    if (use_xb)
        k_xb<<<dim3(8192), dim3(256), 0, stream>>>(inp, XB);

    void* args[] = {(void*)&inp, (void*)&XB, (void*)&use_xb,
                    (void*)&bz, (void*)&br, (void*)&bh,
                    (void*)&HB, (void*)&RH, (void*)&WT, (void*)&flags, (void*)&out};
    const void* fn = ring ? (const void*)gru_persist<1> : (const void*)gru_persist<0>;
    hipError_t e = hipLaunchCooperativeKernel(fn, dim3(NBLK), dim3(256), args, 0, stream);
    if (e != hipSuccess) {
        if (ring)
            gru_persist<1><<<dim3(NBLK), dim3(256), 0, stream>>>(inp, XB, use_xb, bz, br, bh,
                                                                 HB, RH, WT, flags, out);
        else
            gru_persist<0><<<dim3(NBLK), dim3(256), 0, stream>>>(inp, XB, use_xb, bz, br, bh,
                                                                 HB, RH, WT, flags, out);
    }
}